// Round 6
// baseline (192.264 us; speedup 1.0000x reference)
//
#include <hip/hip_runtime.h>
#include <math.h>

#define Hn 512
#define Nn 32
#define Bn 8
#define Ln 4096
#define NF 4096            // complex FFT length (= 16^3)
#define NT 256             // threads per WG
#define ROWF 4097          // float2 stride per channel row in KF workspace
#define TWOPI 6.28318530717958647692f

// ---------------- complex helpers ----------------
__device__ __forceinline__ float2 cmulf(float2 a, float2 b) {
    return make_float2(a.x * b.x - a.y * b.y, a.x * b.y + a.y * b.x);
}
__device__ __forceinline__ float2 caddf(float2 a, float2 b) { return make_float2(a.x + b.x, a.y + b.y); }
__device__ __forceinline__ float2 csubf(float2 a, float2 b) { return make_float2(a.x - b.x, a.y - b.y); }

// LDS dword swizzle: conflict-free (<=2 lanes/bank) for all stage/pointwise patterns below
__device__ __forceinline__ int SW(int a) { return a ^ ((a >> 5) & 31); }
// storage position of frequency k after DIF stages stride 256, 16, 1
__device__ __forceinline__ int pos4(int k) { return ((k & 15) << 8) | (((k >> 4) & 15) << 4) | ((k >> 8) & 15); }

__device__ __forceinline__ float2 ldz(const float* ZR, const float* ZI, int a) {
    int s = SW(a);
    return make_float2(ZR[s], ZI[s]);
}
__device__ __forceinline__ void stz(float* ZR, float* ZI, int a, float2 v) {
    int s = SW(a);
    ZR[s] = v.x;
    ZI[s] = v.y;
}

// ---------------- in-register DFT-16 ----------------
template <int SGN>
__device__ __forceinline__ void dft4(float2& a0, float2& a1, float2& a2, float2& a3) {
    float2 t0 = caddf(a0, a2), t1 = csubf(a0, a2);
    float2 t2 = caddf(a1, a3), t3 = csubf(a1, a3);
    float2 it3 = (SGN < 0) ? make_float2(t3.y, -t3.x) : make_float2(-t3.y, t3.x);
    a0 = caddf(t0, t2);
    a2 = csubf(t0, t2);
    a1 = caddf(t1, it3);
    a3 = csubf(t1, it3);
}

// natural-order input; output freq r lands in x[sl(r)], sl(r)=((r&3)<<2)|(r>>2)
// ZTOP: inputs x[8..15] are known-zero (never read)
template <int SGN, bool ZTOP>
__device__ __forceinline__ void dft16(float2* x) {
    const float C1 = 0.92387953251128675613f, S1 = 0.38268343236508977173f, R2 = 0.70710678118654752440f;
    const float sg = (SGN < 0) ? -1.f : 1.f;
    if (ZTOP) {
#pragma unroll
        for (int q = 0; q < 4; ++q) {
            float2 xa = x[q], xb = x[q + 4];
            float2 it3 = (SGN < 0) ? make_float2(xb.y, -xb.x) : make_float2(-xb.y, xb.x);
            x[q] = caddf(xa, xb);
            x[q + 8] = csubf(xa, xb);
            x[q + 4] = caddf(xa, it3);
            x[q + 12] = csubf(xa, it3);
        }
    } else {
#pragma unroll
        for (int q = 0; q < 4; ++q) dft4<SGN>(x[q], x[q + 4], x[q + 8], x[q + 12]);
    }
    const float2 w1 = make_float2(C1, sg * S1);
    const float2 w2 = make_float2(R2, sg * R2);
    const float2 w3 = make_float2(S1, sg * C1);
    const float2 w6 = make_float2(-R2, sg * R2);
    const float2 w9 = make_float2(-C1, -sg * S1);
    x[5] = cmulf(x[5], w1);
    x[9] = cmulf(x[9], w2);
    x[13] = cmulf(x[13], w3);
    x[6] = cmulf(x[6], w2);
    x[10] = make_float2(-sg * x[10].y, sg * x[10].x);
    x[14] = cmulf(x[14], w6);
    x[7] = cmulf(x[7], w3);
    x[11] = cmulf(x[11], w6);
    x[15] = cmulf(x[15], w9);
#pragma unroll
    for (int a = 0; a < 4; ++a) dft4<SGN>(x[4 * a + 0], x[4 * a + 1], x[4 * a + 2], x[4 * a + 3]);
}

// middle/last LDS stage. TW: apply stage twiddle (last stage has none).
// Twiddles via running recurrence: ONE live float2 instead of a 16-entry table.
template <int SGN, bool TW>
__device__ void stage_lds(float* ZR, float* ZI, int base, int stride, float tau) {
    float2 x[16];
#pragma unroll
    for (int p = 0; p < 16; ++p) x[p] = ldz(ZR, ZI, base + stride * p);
    if (SGN < 0) {
        dft16<SGN, false>(x);
        if (TW) {
            float s, c;
            __sincosf(TWOPI * tau, &s, &c);
            float2 w1 = make_float2(c, -s);
            float2 w = w1;
            stz(ZR, ZI, base, x[0]);
#pragma unroll
            for (int r = 1; r < 16; ++r) {
                int sl = ((r & 3) << 2) | (r >> 2);
                stz(ZR, ZI, base + stride * r, cmulf(x[sl], w));
                w = cmulf(w, w1);
            }
        } else {
#pragma unroll
            for (int r = 0; r < 16; ++r) {
                int sl = ((r & 3) << 2) | (r >> 2);
                stz(ZR, ZI, base + stride * r, x[sl]);
            }
        }
    } else {
        if (TW) {
            float s, c;
            __sincosf(TWOPI * tau, &s, &c);
            float2 w1 = make_float2(c, s);
            float2 w = w1;
#pragma unroll
            for (int r = 1; r < 16; ++r) {
                x[r] = cmulf(x[r], w);
                w = cmulf(w, w1);
            }
        }
        dft16<SGN, false>(x);
#pragma unroll
        for (int n = 0; n < 16; ++n) {
            int sl = ((n & 3) << 2) | (n >> 2);
            stz(ZR, ZI, base + stride * n, x[sl]);
        }
    }
}

// forward stage A: dft16 already done by caller; apply w_4096^{j r} (running) and scatter
__device__ __forceinline__ void scatterA(float* ZR, float* ZI, int j, float2* x) {
    float s, c;
    __sincosf(TWOPI * (float)j * (1.f / 4096.f), &s, &c);
    float2 w1 = make_float2(c, -s);
    float2 w = w1;
    stz(ZR, ZI, j, x[0]);
#pragma unroll
    for (int r = 1; r < 16; ++r) {
        int sl = ((r & 3) << 2) | (r >> 2);
        stz(ZR, ZI, j + 256 * r, cmulf(x[sl], w));
        w = cmulf(w, w1);
    }
}

// rfft untangle + kernel-multiply + irfft re-tangle for the pair (k, 4096-k), in place
__device__ __forceinline__ void pointwise_pair(float* ZR, float* ZI, int k, float2 KA, float2 KB) {
    int pk = pos4(k), pm = pos4((NF - k) & (NF - 1));
    float2 Xk = ldz(ZR, ZI, pk), Xm = ldz(ZR, ZI, pm);
    float2 E = make_float2(0.5f * (Xk.x + Xm.x), 0.5f * (Xk.y - Xm.y));
    float2 O = make_float2(0.5f * (Xk.y + Xm.y), -0.5f * (Xk.x - Xm.x));
    float s, c;
    __sincosf(-TWOPI * (float)k * (1.f / 8192.f), &s, &c);   // w = e^{-2pi i k/8192}
    float2 P = cmulf(make_float2(c, s), O);
    float2 Vk = caddf(E, P);
    float2 Vm = make_float2(E.x - P.x, -(E.y - P.y));        // conj(E - P)
    float2 Yk = cmulf(Vk, KA);
    float2 Ym = cmulf(Vm, KB);
    float2 Ze = make_float2(0.5f * (Yk.x + Ym.x), 0.5f * (Yk.y - Ym.y));
    float2 T = make_float2(0.5f * (Yk.x - Ym.x), 0.5f * (Yk.y + Ym.y));
    float2 Zo = make_float2(c * T.x + s * T.y, c * T.y - s * T.x);  // conj(w)*T
    stz(ZR, ZI, pk, make_float2(Ze.x - Zo.y, Ze.y + Zo.x));         // Ze + i Zo
    stz(ZR, ZI, pm, make_float2(Ze.x + Zo.y, -Ze.y + Zo.x));        // conj(Ze) + i conj(Zo)
}

// shared per-(h,n) constant setup into LDS
__device__ __forceinline__ void setup_cst(float CST[Nn][14], int h, int j,
                                          const float* __restrict__ log_dt,
                                          const float* __restrict__ lnA,
                                          const float* __restrict__ A_im,
                                          const float* __restrict__ B_ri,
                                          const float* __restrict__ C_ri) {
    if (j < Nn) {
        int n = j, idx = h * Nn + n;
        float dt = __expf(log_dt[h]);
        float are = -__expf(lnA[idx]);
        float aim = A_im[idx];
        float dre = dt * are;
        double taud = fmod((double)dt * (double)aim * 0.15915494309189533577, 1.0);
        if (taud < 0.0) taud += 1.0;
        float tau_hi = truncf((float)taud * 4096.f) * (1.f / 4096.f);
        float tau_lo = (float)(taud - (double)tau_hi);
        float s0, c0;
        __sincosf(TWOPI * (float)taud, &s0, &c0);
        float er = __expf(dre);
        float2 w = make_float2(er * c0, er * s0);               // e^{dt A}
        float inv2 = 1.f / (are * are + aim * aim);
        float2 num = make_float2(w.x - 1.f, w.y);
        float2 disc = make_float2((num.x * are + num.y * aim) * inv2,
                                  (num.y * are - num.x * aim) * inv2);   // (e^{dtA}-1)/A
        float2 Bc = make_float2(B_ri[2 * idx], B_ri[2 * idx + 1]);
        float2 CB = cmulf(Bc, disc);
        int i1 = Hn * Nn + idx;
        float2 cA = cmulf(make_float2(C_ri[2 * idx], C_ri[2 * idx + 1]), CB);
        cA.x *= 2.f; cA.y *= 2.f;
        float2 cC = cmulf(make_float2(C_ri[2 * i1], C_ri[2 * i1 + 1]), CB);
        cC.x *= 2.f; cC.y *= 2.f;
        float2 cB2 = cmulf(cA, w);
        float einv = __expf(-2.f * dre);
        float2 winv = make_float2(w.x * einv, -w.y * einv);      // w^{-1}
        float2 cD = cmulf(cC, winv);
        double t512 = fmod(512.0 * taud, 1.0);
        float e512 = __expf(512.f * dre);
        float sR, cR;
        __sincosf(TWOPI * (float)t512, &sR, &cR);
        CST[n][0] = cA.x;  CST[n][1] = cA.y;
        CST[n][2] = cB2.x; CST[n][3] = cB2.y;
        CST[n][4] = cC.x;  CST[n][5] = cC.y;
        CST[n][6] = cD.x;  CST[n][7] = cD.y;
        CST[n][8] = e512 * cR; CST[n][9] = e512 * sR;            // R512 = w^{512}
        CST[n][10] = dre; CST[n][11] = tau_hi; CST[n][12] = tau_lo;
    }
}

// ---------------- kernel 1a: time-domain kernel generation (half-channel per WG) ----------------
// q=0: packed samples m = j + 256p, p=0..7 (causal half)
// q=1: packed samples m = j + 256(8+p)   (anticausal half, reversed)
__global__ __launch_bounds__(NT, 4) void k_gen(const float* __restrict__ log_dt,
                                               const float* __restrict__ lnA,
                                               const float* __restrict__ A_im,
                                               const float* __restrict__ B_ri,
                                               const float* __restrict__ C_ri,
                                               float2* __restrict__ KT) {
    __shared__ float CST[Nn][14];
    int wg = blockIdx.x;
    int h = wg & 511, q = wg >> 9;
    int j = threadIdx.x;
    setup_cst(CST, h, j, log_dt, lnA, A_im, B_ri, C_ri);
    __syncthreads();

    float2 acc[8];
#pragma unroll
    for (int p = 0; p < 8; ++p) acc[p] = make_float2(0.f, 0.f);
    float2* row = KT + (size_t)h * ROWF;

    if (q == 0) {
        float l_lo = (float)(2 * j);
        for (int n = 0; n < Nn; ++n) {
            float2 cA = make_float2(CST[n][0], CST[n][1]);
            float2 cB2 = make_float2(CST[n][2], CST[n][3]);
            float2 R = make_float2(CST[n][8], CST[n][9]);
            float dre = CST[n][10], thi = CST[n][11], tlo = CST[n][12];
            float ph = l_lo * thi;
            ph -= floorf(ph);
            ph += l_lo * tlo;
            ph -= floorf(ph);
            float s, c;
            __sincosf(TWOPI * ph, &s, &c);
            float m0 = __expf(dre * l_lo);
            float2 qv = make_float2(m0 * c, m0 * s);             // w^{2j}
#pragma unroll
            for (int p = 0; p < 8; ++p) {
                acc[p].x += cA.x * qv.x - cA.y * qv.y;
                acc[p].y += cB2.x * qv.x - cB2.y * qv.y;
                qv = cmulf(qv, R);
            }
        }
#pragma unroll
        for (int p = 0; p < 8; ++p) row[j + 256 * p] = acc[p];
    } else {
        float l_hi = (float)(511 - 2 * j);
        for (int n = 0; n < Nn; ++n) {
            float2 cC = make_float2(CST[n][4], CST[n][5]);
            float2 cD = make_float2(CST[n][6], CST[n][7]);
            float2 R = make_float2(CST[n][8], CST[n][9]);
            float dre = CST[n][10], thi = CST[n][11], tlo = CST[n][12];
            float ph2 = l_hi * thi;
            ph2 -= floorf(ph2);
            ph2 += l_hi * tlo;
            ph2 -= floorf(ph2);
            float s2, c2;
            __sincosf(TWOPI * ph2, &s2, &c2);
            float m1 = __expf(dre * l_hi);
            float2 r = make_float2(m1 * c2, m1 * s2);            // w^{511-2j}, decaying iteration
#pragma unroll
            for (int p = 7; p >= 0; --p) {
                acc[p].x += cC.x * r.x - cC.y * r.y;
                acc[p].y += cD.x * r.x - cD.y * r.y;
                r = cmulf(r, R);
            }
        }
#pragma unroll
        for (int p = 0; p < 8; ++p) row[j + 256 * (8 + p)] = acc[p];
    }
}

// ---------------- kernel 1b: FFT of time-domain kernel, in-place row -> KF spectrum ----------------
// Safe in-place: all global reads complete before barrier 1; KF writes happen after barrier 3.
__global__ __launch_bounds__(NT, 2) void k_fft(const float* __restrict__ D,
                                               float2* __restrict__ KF) {
    __shared__ float ZR[NF];
    __shared__ float ZI[NF];
    int h = blockIdx.x, j = threadIdx.x;
    float2* row = KF + (size_t)h * ROWF;
    float2 x[16];
#pragma unroll
    for (int p = 0; p < 16; ++p) x[p] = row[j + 256 * p];
    dft16<-1, false>(x);
    scatterA(ZR, ZI, j, x);
    __syncthreads();
    stage_lds<-1, true>(ZR, ZI, ((j >> 4) << 8) | (j & 15), 16, (float)(j & 15) * (1.f / 256.f));
    __syncthreads();
    stage_lds<-1, false>(ZR, ZI, j << 4, 1, 0.f);
    __syncthreads();
    // untangle to rfft bins; store in pointwise-permuted, coalesced layout; +D ; x 1/4096
    float Dh = D[h];
    const float inv = 1.f / 4096.f;
#pragma unroll
    for (int jj = 0; jj < 8; ++jj) {
        int k = ((j & 7) << 8) | (jj << 5) | (j >> 3);
        int pk = pos4(k), pm = pos4((NF - k) & (NF - 1));
        float2 Xk = ldz(ZR, ZI, pk), Xm = ldz(ZR, ZI, pm);
        float2 E = make_float2(0.5f * (Xk.x + Xm.x), 0.5f * (Xk.y - Xm.y));
        float2 O = make_float2(0.5f * (Xk.y + Xm.y), -0.5f * (Xk.x - Xm.x));
        float s, c;
        __sincosf(-TWOPI * (float)k * (1.f / 8192.f), &s, &c);
        float2 P = cmulf(make_float2(c, s), O);
        row[jj * 256 + j] = make_float2((E.x + P.x + Dh) * inv, (E.y + P.y) * inv);
        row[2048 + jj * 256 + j] = make_float2((E.x - P.x + Dh) * inv, -(E.y - P.y) * inv);
    }
    if (j == NT - 1) {  // bin k = 2048 (self-paired)
        float2 Xk = ldz(ZR, ZI, pos4(2048));
        row[4096] = make_float2((Xk.x + Dh) * inv, -Xk.y * inv);
    }
}

// ---------------- kernel 2: FFT convolution, one (batch,channel) per WG ----------------
__global__ __launch_bounds__(NT, 4) void k_conv(const float* __restrict__ u,
                                                const float2* __restrict__ KF,
                                                float* __restrict__ y) {
    __shared__ float ZR[NF];
    __shared__ float ZI[NF];
    int wg = blockIdx.x;
    int h = wg & 511, b = wg >> 9;   // same h -> same XCD (h%8 == wg%8): KF row stays in XCD L2
    int j = threadIdx.x;
    const float2* u2 = (const float2*)(u + ((size_t)b * Hn + h) * Ln);
    // forward stage A fused with load; upper half of padded input is zero
    float2 x[16];
#pragma unroll
    for (int p = 0; p < 8; ++p) x[p] = u2[j + 256 * p];
    dft16<-1, true>(x);
    scatterA(ZR, ZI, j, x);
    __syncthreads();
    stage_lds<-1, true>(ZR, ZI, ((j >> 4) << 8) | (j & 15), 16, (float)(j & 15) * (1.f / 256.f));
    __syncthreads();
    stage_lds<-1, false>(ZR, ZI, j << 4, 1, 0.f);
    __syncthreads();
    // pointwise multiply (rfft untangle -> *KF -> irfft tangle), permuted coalesced KF reads
    const float2* row = KF + (size_t)h * ROWF;
#pragma unroll
    for (int jj = 0; jj < 8; ++jj) {
        int k = ((j & 7) << 8) | (jj << 5) | (j >> 3);
        pointwise_pair(ZR, ZI, k, row[jj * 256 + j], row[2048 + jj * 256 + j]);
    }
    if (j == NT - 1) pointwise_pair(ZR, ZI, 2048, row[4096], row[4096]);
    __syncthreads();
    // inverse stages
    stage_lds<1, false>(ZR, ZI, j << 4, 1, 0.f);
    __syncthreads();
    stage_lds<1, true>(ZR, ZI, ((j >> 4) << 8) | (j & 15), 16, (float)(j & 15) * (1.f / 256.f));
    __syncthreads();
    // inverse stage A' fused with store; only first half of time outputs needed
    float2 xx[16];
#pragma unroll
    for (int p = 0; p < 16; ++p) xx[p] = ldz(ZR, ZI, j + 256 * p);
    {
        float s, c;
        __sincosf(TWOPI * (float)j * (1.f / 4096.f), &s, &c);
        float2 w1 = make_float2(c, s);
        float2 w = w1;
#pragma unroll
        for (int r = 1; r < 16; ++r) {
            xx[r] = cmulf(xx[r], w);
            w = cmulf(w, w1);
        }
    }
    dft16<1, false>(xx);
    float2* y2 = (float2*)(y + ((size_t)b * Hn + h) * Ln);
#pragma unroll
    for (int n = 0; n < 8; ++n) {
        int sl = ((n & 3) << 2) | (n >> 2);
        y2[j + 256 * n] = xx[sl];
    }
}

extern "C" void kernel_launch(void* const* d_in, const int* in_sizes, int n_in,
                              void* d_out, int out_size, void* d_ws, size_t ws_size,
                              hipStream_t stream) {
    const float* u = (const float*)d_in[0];
    const float* log_dt = (const float*)d_in[1];
    const float* lnA = (const float*)d_in[2];
    const float* A_im = (const float*)d_in[3];
    const float* B_ri = (const float*)d_in[4];
    const float* C_ri = (const float*)d_in[5];
    const float* D = (const float*)d_in[6];
    float* y = (float*)d_out;
    float2* KF = (float2*)d_ws;   // Hn * ROWF float2 = ~16.78 MB (time-domain staged in place)

    k_gen<<<2 * Hn, NT, 0, stream>>>(log_dt, lnA, A_im, B_ri, C_ri, KF);
    k_fft<<<Hn, NT, 0, stream>>>(D, KF);
    k_conv<<<Bn * Hn, NT, 0, stream>>>(u, KF, y);
}